// Round 3
// baseline (773.455 us; speedup 1.0000x reference)
//
#include <hip/hip_runtime.h>
#include <hip/hip_bf16.h>

typedef __attribute__((ext_vector_type(8)))  short bf16x8;
typedef __attribute__((ext_vector_type(4)))  float f32x4;
typedef __attribute__((ext_vector_type(16))) float f32x16;

#define LQ   0
#define LK   16384
#define LVT  32768
#define LSCR 49152
#define MFMA(A,B,C) __builtin_amdgcn_mfma_f32_32x32x16_bf16(A,B,C,0,0,0)

__device__ __forceinline__ short f2bf(float f){
  union { float f; unsigned u; } v; v.f = f;
  unsigned r = v.u + 0x7FFFu + ((v.u >> 16) & 1u);
  return (short)(r >> 16);
}
// Q/K tiles: [token][d] bf16, pitch 256B, 16-slot XOR swizzle.
__device__ __forceinline__ int adrQK(int base, int row, int col){
  return (base + row*256 + col*2) ^ ((row & 15) << 4);
}
// V^T tile: [d][token] bf16; d-pairs share a 256B row. 16-slot swizzle.
__device__ __forceinline__ int adrVT(int d, int kt){
  return (LVT + (d >> 1)*256 + (d & 1)*128 + kt*2) ^ (((d >> 1) & 15) << 4);
}
// wave-private scratch: [q(0..31)][j(0..63)] bf16, pitch 128B, 8-slot swizzle
__device__ __forceinline__ int adrS(int wvid, int q, int j){
  return (LSCR + wvid*4096 + q*128 + j*2) ^ ((q & 7) << 4);
}
__device__ __forceinline__ f32x16 zero16(){
  f32x16 z;
#pragma unroll
  for (int i = 0; i < 16; ++i) z[i] = 0.f;
  return z;
}
__device__ __forceinline__ bf16x8 lds8(const char* smem, int off){
  return *(const bf16x8*)(smem + off);
}

__global__ void cvt4(const float* __restrict__ a, const float* __restrict__ b,
                     const float* __restrict__ c, const float* __restrict__ d,
                     short* __restrict__ dst) {
  int i = blockIdx.x * 256 + threadIdx.x;
  int which = i >> 17, off = i & 131071;
  const float* s = (which == 0) ? a : (which == 1) ? b : (which == 2) ? c : d;
  dst[i] = f2bf(s[off]);
}

__global__ __launch_bounds__(256, 2) void swattn_main(
    const float* __restrict__ x, const float* __restrict__ mask,
    const float* __restrict__ Bp,
    const float* __restrict__ wq_b, const float* __restrict__ wk_b,
    const float* __restrict__ wv_b, const float* __restrict__ proj_b,
    const short* __restrict__ wq, const short* __restrict__ wk,
    const short* __restrict__ wv, const short* __restrict__ pw,
    float* __restrict__ out)
{
  __shared__ alignas(16) char smem[65536];
  const int tid  = threadIdx.x;
  const int wvid = tid >> 6;
  const int lane = tid & 63;
  const int c    = lane & 31;   // MFMA col / A-row lane index
  const int hh   = lane >> 5;   // k-group
  const int qb   = wvid >> 1;   // q-block (32 tokens)
  const int dh   = wvid & 1;    // d-half (64 dims)
  const int wid = blockIdx.x;
  const int bb = wid >> 8, wy = (wid >> 4) & 15, wx = wid & 15;

  // ---- gather shifted window into LDS (region LQ) as bf16 ----
  {
    int token = tid >> 2, q = tid & 3;
    int py = token >> 3, px = token & 7;
    int Y = (wy*8 + py + 4) & 127;
    int X = (wx*8 + px + 4) & 127;
    int swin = bb*256 + ((Y>>3)<<4) + (X>>3);
    int stok = ((Y&7)<<3) + (X&7);
    const float* src = x + ((size_t)(swin*64 + stok))*128 + q*32;
#pragma unroll
    for (int j = 0; j < 32; j += 8) {
      f32x4 f0 = *(const f32x4*)(src + j);
      f32x4 f1 = *(const f32x4*)(src + j + 4);
      bf16x8 bv;
      bv[0]=f2bf(f0[0]); bv[1]=f2bf(f0[1]); bv[2]=f2bf(f0[2]); bv[3]=f2bf(f0[3]);
      bv[4]=f2bf(f1[0]); bv[5]=f2bf(f1[1]); bv[6]=f2bf(f1[2]); bv[7]=f2bf(f1[3]);
      *(bf16x8*)(smem + adrQK(LQ, token, q*32 + j)) = bv;
    }
  }
  __syncthreads();

  // ---- hold full XW tile in registers as A-fragments (rows c, 32+c) ----
  bf16x8 xwf0[8], xwf1[8];
#pragma unroll
  for (int cs = 0; cs < 8; ++cs) {
    xwf0[cs] = lds8(smem, adrQK(LQ, c,      cs*16 + hh*8));
    xwf1[cs] = lds8(smem, adrQK(LQ, 32 + c, cs*16 + hh*8));
  }
  __syncthreads();   // LQ now reusable for Q

  f32x16 y[4];
#pragma unroll
  for (int ct = 0; ct < 4; ++ct) y[ct] = zero16();

  const float isdk = 0.088388347648318447f;  // 1/sqrt(128)
  const float* mrow = nullptr;
  if (wy == 15 && wx != 15)      mrow = mask;
  else if (wx == 15 && wy != 15) mrow = mask + 4096;
  else if (wy == 15 && wx == 15) mrow = mask + 8192;

  for (int hd = 0; hd < 8; ++hd) {
    // ======== Phase 1: cooperative QKV (each wave: 32-dim slice of each) ====
#pragma unroll
    for (int jp = 0; jp < 3; ++jp) {
      const short* wbase = (jp==0) ? wq : (jp==1) ? wk : wv;
      const float* bbase = (jp==0) ? wq_b : (jp==1) ? wk_b : wv_b;
      const short* wrow = wbase + (size_t)(hd*128 + wvid*32 + c)*128;
      f32x16 acc0 = zero16(), acc1 = zero16();
#pragma unroll
      for (int cs = 0; cs < 8; ++cs) {
        bf16x8 wf = *(const bf16x8*)(wrow + cs*16 + hh*8);
        if (jp < 2) {
          acc0 = MFMA(xwf0[cs], wf, acc0);   // D[token][j]
          acc1 = MFMA(xwf1[cs], wf, acc1);
        } else {
          acc0 = MFMA(wf, xwf0[cs], acc0);   // D[d][token]
          acc1 = MFMA(wf, xwf1[cs], acc1);
        }
      }
      if (jp < 2) {
        float bias = bbase[hd*128 + wvid*32 + c];
        int base = (jp==0) ? LQ : LK;
#pragma unroll
        for (int r = 0; r < 16; ++r) {
          int rp = (r&3) + 8*(r>>2) + 4*hh;
          *(short*)(smem + adrQK(base, rp,      wvid*32 + c)) = f2bf(acc0[r] + bias);
          *(short*)(smem + adrQK(base, 32 + rp, wvid*32 + c)) = f2bf(acc1[r] + bias);
        }
      } else {
#pragma unroll
        for (int r = 0; r < 16; ++r) {
          int rp = (r&3) + 8*(r>>2) + 4*hh;
          float bias = bbase[hd*128 + wvid*32 + rp];
          *(short*)(smem + adrVT(wvid*32 + rp, c))      = f2bf(acc0[r] + bias);
          *(short*)(smem + adrVT(wvid*32 + rp, 32 + c)) = f2bf(acc1[r] + bias);
        }
      }
    }
    __syncthreads();

    // ======== Phase 2: S^T = K·Q^T, softmax in registers ========
    f32x16 a0 = zero16(), a1 = zero16();
#pragma unroll
    for (int ds = 0; ds < 8; ++ds) {
      bf16x8 qf = lds8(smem, adrQK(LQ, qb*32 + c, ds*16 + hh*8));
      bf16x8 k0 = lds8(smem, adrQK(LK, c,         ds*16 + hh*8));
      bf16x8 k1 = lds8(smem, adrQK(LK, 32 + c,    ds*16 + hh*8));
      a0 = MFMA(k0, qf, a0);   // rows: keys 0..31, cols: q tokens qb*32+c
      a1 = MFMA(k1, qf, a1);   // rows: keys 32..63
    }
    {
      const float* bprow = Bp + (qb*32 + c)*64;
#pragma unroll
      for (int r = 0; r < 16; ++r) {
        int rp = (r&3) + 8*(r>>2) + 4*hh;
        a0[r] = a0[r]*isdk + bprow[rp];
        a1[r] = a1[r]*isdk + bprow[32 + rp];
      }
      float mx = a0[0];
#pragma unroll
      for (int r = 1; r < 16; ++r) mx = fmaxf(mx, a0[r]);
#pragma unroll
      for (int r = 0; r < 16; ++r) mx = fmaxf(mx, a1[r]);
      mx = fmaxf(mx, __shfl_xor(mx, 32, 64));
      float sum = 0.f;
#pragma unroll
      for (int r = 0; r < 16; ++r) { a0[r] = __expf(a0[r]-mx); sum += a0[r]; }
#pragma unroll
      for (int r = 0; r < 16; ++r) { a1[r] = __expf(a1[r]-mx); sum += a1[r]; }
      sum += __shfl_xor(sum, 32, 64);
      float inv = 1.0f / sum;
#pragma unroll
      for (int r = 0; r < 16; ++r) { a0[r] *= inv; a1[r] *= inv; }
      if (mrow) {
        const float* mr = mrow + (qb*32 + c)*64;
#pragma unroll
        for (int r = 0; r < 16; ++r) {
          int rp = (r&3) + 8*(r>>2) + 4*hh;
          a0[r] *= mr[rp];
          a1[r] *= mr[32 + rp];
        }
      }
    }
    // ---- P roundtrip via wave-private scratch: store [q][key], reload B-frags
#pragma unroll
    for (int r = 0; r < 16; ++r) {
      int rp = (r&3) + 8*(r>>2) + 4*hh;
      *(short*)(smem + adrS(wvid, c, rp))      = f2bf(a0[r]);
      *(short*)(smem + adrS(wvid, c, 32 + rp)) = f2bf(a1[r]);
    }
    asm volatile("s_waitcnt lgkmcnt(0)" ::: "memory");
    bf16x8 pf[4];
#pragma unroll
    for (int ks = 0; ks < 4; ++ks)
      pf[ks] = lds8(smem, adrS(wvid, c, ks*16 + hh*8));

    // ======== Phase 3: O^T = V^T · P (this wave's 64-dim half) ========
    f32x16 o0 = zero16(), o1 = zero16();
#pragma unroll
    for (int ks = 0; ks < 4; ++ks) {
      bf16x8 v0 = lds8(smem, adrVT(dh*64 + c,      ks*16 + hh*8));
      bf16x8 v1 = lds8(smem, adrVT(dh*64 + 32 + c, ks*16 + hh*8));
      o0 = MFMA(v0, pf[ks], o0);   // rows: j-local 0..31
      o1 = MFMA(v1, pf[ks], o1);   // rows: j-local 32..63
    }
    // ---- O roundtrip via the same wave-private scratch: [q][j-local] ----
#pragma unroll
    for (int r = 0; r < 16; ++r) {
      int rp = (r&3) + 8*(r>>2) + 4*hh;
      *(short*)(smem + adrS(wvid, c, rp))      = f2bf(o0[r]);
      *(short*)(smem + adrS(wvid, c, 32 + rp)) = f2bf(o1[r]);
    }
    asm volatile("s_waitcnt lgkmcnt(0)" ::: "memory");
    bf16x8 of[4];
#pragma unroll
    for (int ks = 0; ks < 4; ++ks)
      of[ks] = lds8(smem, adrS(wvid, c, ks*16 + hh*8));

    // ======== Phase 4: y^T += pw · O^T ========
#pragma unroll
    for (int ct = 0; ct < 4; ++ct) {
      const short* pr = pw + (size_t)(ct*32 + c)*1024 + hd*128 + dh*64;
#pragma unroll
      for (int ks = 0; ks < 4; ++ks) {
        bf16x8 pwf = *(const bf16x8*)(pr + ks*16 + hh*8);
        y[ct] = MFMA(pwf, of[ks], y[ct]);
      }
    }
    __syncthreads();   // Q/K/VT reads done before next head overwrites
  }

  // ---- epilogue: sum the two d-halves, add bias, reverse-shift scatter ----
  if (dh == 1) {
    int base = qb*16384;   // qb0 -> LQ region, qb1 -> LK region
#pragma unroll
    for (int ct = 0; ct < 4; ++ct)
#pragma unroll
      for (int g = 0; g < 4; ++g) {
        int c0 = ct*32 + 8*g + 4*hh;
        int o = (base + c*512 + c0*4) ^ ((c & 7) << 4);
        f32x4 vv = { y[ct][4*g], y[ct][4*g+1], y[ct][4*g+2], y[ct][4*g+3] };
        *(f32x4*)(smem + o) = vv;
      }
  }
  __syncthreads();
  if (dh == 0) {
    int base = qb*16384;
#pragma unroll
    for (int ct = 0; ct < 4; ++ct)
#pragma unroll
      for (int g = 0; g < 4; ++g) {
        int c0 = ct*32 + 8*g + 4*hh;
        int o = (base + c*512 + c0*4) ^ ((c & 7) << 4);
        f32x4 p = *(const f32x4*)(smem + o);
        y[ct][4*g]   += p[0];
        y[ct][4*g+1] += p[1];
        y[ct][4*g+2] += p[2];
        y[ct][4*g+3] += p[3];
      }
    int q = qb*32 + c;
    int py = q >> 3, px = q & 7;
    int Y = (wy*8 + py + 4) & 127;
    int X = (wx*8 + px + 4) & 127;
    int dwin = bb*256 + ((Y>>3)<<4) + (X>>3);
    int dtok = ((Y&7)<<3) + (X&7);
    float* dst = out + ((size_t)(dwin*64 + dtok))*128;
#pragma unroll
    for (int ct = 0; ct < 4; ++ct)
#pragma unroll
      for (int g = 0; g < 4; ++g) {
        int c0 = ct*32 + 8*g + 4*hh;
        f32x4 pb = *(const f32x4*)(proj_b + c0);
        f32x4 vv = { y[ct][4*g]   + pb[0], y[ct][4*g+1] + pb[1],
                     y[ct][4*g+2] + pb[2], y[ct][4*g+3] + pb[3] };
        *(f32x4*)(dst + c0) = vv;
      }
  }
}

extern "C" void kernel_launch(void* const* d_in, const int* in_sizes, int n_in,
                              void* d_out, int out_size, void* d_ws, size_t ws_size,
                              hipStream_t stream) {
  (void)in_sizes; (void)n_in; (void)out_size; (void)ws_size;
  const float* x      = (const float*)d_in[0];
  const float* mask   = (const float*)d_in[1];
  const float* Bp     = (const float*)d_in[2];
  const float* wq_w   = (const float*)d_in[3];
  const float* wq_b   = (const float*)d_in[4];
  const float* wk_w   = (const float*)d_in[5];
  const float* wk_b   = (const float*)d_in[6];
  const float* wv_w   = (const float*)d_in[7];
  const float* wv_b   = (const float*)d_in[8];
  const float* proj_w = (const float*)d_in[9];
  const float* proj_b = (const float*)d_in[10];
  float* out = (float*)d_out;
  short* wsb = (short*)d_ws;   // [wq|wk|wv|pw] bf16

  cvt4<<<2048, 256, 0, stream>>>(wq_w, wk_w, wv_w, proj_w, wsb);
  swattn_main<<<1024, 256, 0, stream>>>(x, mask, Bp, wq_b, wk_b, wv_b, proj_b,
      wsb, wsb + 131072, wsb + 262144, wsb + 393216, out);
}